// Round 13
// baseline (184.278 us; speedup 1.0000x reference)
//
#include <hip/hip_runtime.h>
#include <hip/hip_cooperative_groups.h>

namespace cg = cooperative_groups;

// CLAHE: B=32, C=3, H=W=512, GRID=8x8 -> TILE=64x64 (4096 px), NUM_BINS=256,
// CLIP_LIMIT=40 -> clip value = 640.
// R13: cooperative fusion of R12's two proven kernels. One block per
// (plane, tile-row) stripe (768 blocks). Phase A = R12 k1 (stream stripe,
// 8 LDS hists, shfl scan -> luts, linear v8). grid.sync. Phase B = R12 k2
// on the block's OWN stripe (2 bands) -> v8 read-back is same-CU L2-hot.
// d_ws: [0, 6.29MB) luts, [6.29MB, +25.2MB) v8.

#define NBINS  256
#define TILE   64
#define CH     3
#define HH     512
#define WW     512
#define CLIPV  640
#define PIXELS 4096   // per tile

#define LUTS_FLOATS (32 * 8 * 8 * 3 * NBINS)          // 1,572,864
#define V8_BYTES    ((size_t)32 * 3 * HH * WW)        // 25,165,824

typedef float f32x4 __attribute__((ext_vector_type(4)));

// ============================ FUSED KERNEL (R13) ==============================
__global__ __launch_bounds__(256) void clahe_fused2(const float* __restrict__ img,
                                                    float* __restrict__ luts,
                                                    unsigned char* __restrict__ v8,
                                                    float* __restrict__ out) {
    __shared__ unsigned int lds[9 * NBINS];   // 9 KB: hist[8][256] (A) / Pack[9][256] (B)

    const int t     = threadIdx.x;
    const int bid   = blockIdx.x;        // = plane*8 + ty
    const int ty    = bid & 7;
    const int plane = bid >> 3;          // b*3 + c
    const int c     = plane % 3;
    const int bb    = plane / 3;

    // ---------------- Phase A: stripe histogram + clip + scan -> luts, v8 -----
    #pragma unroll
    for (int h = 0; h < 8; ++h) lds[h * NBINS + t] = 0u;
    __syncthreads();

    const size_t base = ((size_t)plane * HH + (size_t)ty * TILE) * WW;  // float offset
    const f32x4* __restrict__ src  = reinterpret_cast<const f32x4*>(img + base);
    uchar4*      __restrict__ dst8 = reinterpret_cast<uchar4*>(v8 + base);

    // stripe = 64 rows * 128 float4 = 8192 float4; 256 threads x 32 iters.
    #pragma unroll 4
    for (int it = 0; it < 32; ++it) {
        const int f = it * 256 + t;          // linear float4 index in stripe
        const f32x4 v = src[f];
        const int tile = (f & 127) >> 4;     // 4 px of a float4 share one tile
        atomicAdd(&lds[tile * NBINS + min(max((int)floorf(v.x * 256.0f), 0), 255)], 1u);
        atomicAdd(&lds[tile * NBINS + min(max((int)floorf(v.y * 256.0f), 0), 255)], 1u);
        atomicAdd(&lds[tile * NBINS + min(max((int)floorf(v.z * 256.0f), 0), 255)], 1u);
        atomicAdd(&lds[tile * NBINS + min(max((int)floorf(v.w * 256.0f), 0), 255)], 1u);
        uchar4 q;
        q.x = (unsigned char)min(max((int)floorf(v.x * 255.0f), 0), 255);
        q.y = (unsigned char)min(max((int)floorf(v.y * 255.0f), 0), 255);
        q.z = (unsigned char)min(max((int)floorf(v.z * 255.0f), 0), 255);
        q.w = (unsigned char)min(max((int)floorf(v.w * 255.0f), 0), 255);
        dst8[f] = q;
    }
    __syncthreads();

    // Each of the 4 waves scans 2 histograms (256 bins = 4 chunks of 64).
    const int lane = t & 63;
    const int wid  = t >> 6;
    #pragma unroll
    for (int s = 0; s < 2; ++s) {
        const int h = wid * 2 + s;
        int carry = 0;
        int incl[4];
        #pragma unroll
        for (int ch = 0; ch < 4; ++ch) {
            int v = min((int)lds[h * NBINS + ch * 64 + lane], CLIPV);
            #pragma unroll
            for (int off = 1; off < 64; off <<= 1) {
                int n = __shfl_up(v, off, 64);
                if (lane >= off) v += n;
            }
            incl[ch] = carry + v;
            carry += __shfl(v, 63, 64);      // chunk total from lane 63
        }
        const int total    = carry;
        const int excess   = PIXELS - total;           // >= 0
        const int residual = excess & 255;
        const int redist   = excess >> 8;
        const int job = ((bb * 8 + ty) * 8 + h) * 3 + c;
        float* __restrict__ dst = luts + (size_t)job * NBINS;
        #pragma unroll
        for (int ch = 0; ch < 4; ++ch) {
            const int bin = ch * 64 + lane;
            // inclusive cumsum of (clipped + redist + (bin<residual ? 1 : 0));
            // (nb-1)/pixels = 255/4096 exact in fp32; product <= 255 exact.
            const int cum = incl[ch] + redist * (bin + 1) + min(bin + 1, residual);
            dst[bin] = floorf(fminf((float)cum * (255.0f / 4096.0f), 255.0f));
        }
    }

    __threadfence();            // release luts + v8 to device scope
    cg::this_grid().sync();

    // ---------------- Phase B: apply own stripe (2 bands x 32 rows) -----------
    const unsigned int* __restrict__ v8w = reinterpret_cast<const unsigned int*>(v8 + base);
    f32x4* __restrict__ outw = reinterpret_cast<f32x4*>(out + base);

    // Thread-constant x geometry: this thread always covers pixels x..x+3.
    const int x4f = t & 127;              // float4 column 0..127
    const int x   = x4f * 4;
    const int tx_sel = (x < 32) ? 8 : ((x >= 480) ? 7 : ((x - 32) >> 6));
    const unsigned int* __restrict__ Row = &lds[tx_sel * NBINS];
    float wxv[4];
    #pragma unroll
    for (int i = 0; i < 4; ++i) {
        const int xx = x + i;
        wxv[i] = (xx < 32 || xx >= 480) ? 1.0f
               : (float)(63 - ((xx - 32) & 63)) * (1.0f / 63.0f);
    }

    #pragma unroll 1
    for (int band = 0; band < 2; ++band) {
        const int yb = ty * 64 + band * 32;
        int ty0, ty1;
        if (yb < 32)        { ty0 = 0; ty1 = 0; }
        else if (yb >= 480) { ty0 = 7; ty1 = 7; }
        else                { ty0 = (yb - 32) >> 6; ty1 = ty0 + 1; }
        const int rb0 = (bb * 8 + ty0) * 8;
        const int rb1 = (bb * 8 + ty1) * 8;

        // 16 coalesced 1KB loads (v = t); LUT values are integral 0..255.
        int iL0[8], iL1[8];
        #pragma unroll
        for (int tx = 0; tx < 8; ++tx) {
            iL0[tx] = (int)luts[((size_t)((rb0 + tx) * 3 + c)) * NBINS + t];
            iL1[tx] = (int)luts[((size_t)((rb1 + tx) * 3 + c)) * NBINS + t];
        }
        __syncthreads();   // prior use of lds fully read (scan / previous band)
        #pragma unroll
        for (int tx = 0; tx < 8; ++tx) {
            int txn = (tx < 7) ? tx + 1 : 7;
            lds[tx * NBINS + t] = (unsigned)(iL1[tx] | (iL1[txn] << 8) |
                                             (iL0[tx] << 16) | (iL0[txn] << 24));
        }
        lds[8 * NBINS + t] = (unsigned)(iL1[0] | (iL1[0] << 8) |
                                        (iL0[0] << 16) | (iL0[0] << 24));
        __syncthreads();

        // band rows: it = band*16 .. band*16+15 (fi>>7 = rows band*32..+31)
        #pragma unroll 4
        for (int it = band * 16; it < band * 16 + 16; ++it) {
            const int fi  = it * 256 + t;     // lane-consecutive float4 index
            const int row = fi >> 7;
            const int y   = ty * 64 + row;
            // On edge bands L0==L1 -> slope 0 -> wy's value irrelevant; safe.
            const float wy = (float)(63 - ((y - 32) & 63)) * (1.0f / 63.0f);

            const unsigned int w = v8w[fi];   // own-stripe v8: L2-hot
            f32x4 res;
            #pragma unroll
            for (int i = 0; i < 4; ++i) {
                const int vv = (w >> (8 * i)) & 255;
                const unsigned int raw = Row[vv];
                const float l1a = (float)(raw & 255u);
                const float l1b = (float)((raw >> 8) & 255u);
                const float l0a = (float)((raw >> 16) & 255u);
                const float l0b = (float)(raw >> 24);
                const float r0 = fmaf(wy, l0a - l1a, l1a);
                const float r1 = fmaf(wy, l0b - l1b, l1b);
                res[i] = fmaf(wxv[i], r0 - r1, r1) * (1.0f / 255.0f);
            }
            outw[fi] = res;
        }
    }
}

// ===================== FALLBACK (known-good R12 two-kernel path) ==============
__global__ __launch_bounds__(256) void clahe_hist_lut_stripe(const float* __restrict__ img,
                                                             float* __restrict__ luts,
                                                             unsigned char* __restrict__ v8,
                                                             int write_v8) {
    const int t     = threadIdx.x;
    const int bid   = blockIdx.x;
    const int ty    = bid & 7;
    const int plane = bid >> 3;
    const int c     = plane % 3;
    const int bb    = plane / 3;

    __shared__ unsigned int hist[8][NBINS];
    #pragma unroll
    for (int h = 0; h < 8; ++h) hist[h][t] = 0u;
    __syncthreads();

    const size_t base = ((size_t)plane * HH + (size_t)ty * TILE) * WW;
    const f32x4* __restrict__ src  = reinterpret_cast<const f32x4*>(img + base);
    uchar4*      __restrict__ dst8 = reinterpret_cast<uchar4*>(v8 + base);

    #pragma unroll 4
    for (int it = 0; it < 32; ++it) {
        const int f = it * 256 + t;
        const f32x4 v = src[f];
        const int tile = (f & 127) >> 4;
        atomicAdd(&hist[tile][min(max((int)floorf(v.x * 256.0f), 0), 255)], 1u);
        atomicAdd(&hist[tile][min(max((int)floorf(v.y * 256.0f), 0), 255)], 1u);
        atomicAdd(&hist[tile][min(max((int)floorf(v.z * 256.0f), 0), 255)], 1u);
        atomicAdd(&hist[tile][min(max((int)floorf(v.w * 256.0f), 0), 255)], 1u);
        if (write_v8) {
            uchar4 q;
            q.x = (unsigned char)min(max((int)floorf(v.x * 255.0f), 0), 255);
            q.y = (unsigned char)min(max((int)floorf(v.y * 255.0f), 0), 255);
            q.z = (unsigned char)min(max((int)floorf(v.z * 255.0f), 0), 255);
            q.w = (unsigned char)min(max((int)floorf(v.w * 255.0f), 0), 255);
            dst8[f] = q;
        }
    }
    __syncthreads();

    const int lane = t & 63;
    const int wid  = t >> 6;
    #pragma unroll
    for (int s = 0; s < 2; ++s) {
        const int h = wid * 2 + s;
        int carry = 0;
        int incl[4];
        #pragma unroll
        for (int ch = 0; ch < 4; ++ch) {
            int v = min((int)hist[h][ch * 64 + lane], CLIPV);
            #pragma unroll
            for (int off = 1; off < 64; off <<= 1) {
                int n = __shfl_up(v, off, 64);
                if (lane >= off) v += n;
            }
            incl[ch] = carry + v;
            carry += __shfl(v, 63, 64);
        }
        const int total    = carry;
        const int excess   = PIXELS - total;
        const int residual = excess & 255;
        const int redist   = excess >> 8;
        const int job = ((bb * 8 + ty) * 8 + h) * 3 + c;
        float* __restrict__ dst = luts + (size_t)job * NBINS;
        #pragma unroll
        for (int ch = 0; ch < 4; ++ch) {
            const int bin = ch * 64 + lane;
            const int cum = incl[ch] + redist * (bin + 1) + min(bin + 1, residual);
            dst[bin] = floorf(fminf((float)cum * (255.0f / 4096.0f), 255.0f));
        }
    }
}

template<bool USE_V8>
__global__ __launch_bounds__(256) void clahe_apply_band(const float* __restrict__ img,
                                                        const unsigned char* __restrict__ v8,
                                                        const float* __restrict__ luts,
                                                        float* __restrict__ out) {
    __shared__ unsigned int Pack[9][NBINS];

    const int t     = threadIdx.x;
    const int bid   = blockIdx.x;
    const int g     = bid & 15;
    const int plane = bid >> 4;
    const int c     = plane % 3;
    const int bb    = plane / 3;
    const int y0    = g * 32;

    int ty0, ty1;
    if (y0 < 32)        { ty0 = 0; ty1 = 0; }
    else if (y0 >= 480) { ty0 = 7; ty1 = 7; }
    else                { ty0 = (y0 - 32) >> 6; ty1 = ty0 + 1; }

    const int rb0 = (bb * 8 + ty0) * 8;
    const int rb1 = (bb * 8 + ty1) * 8;

    int iL0[8], iL1[8];
    #pragma unroll
    for (int tx = 0; tx < 8; ++tx) {
        iL0[tx] = (int)luts[((size_t)((rb0 + tx) * 3 + c)) * NBINS + t];
        iL1[tx] = (int)luts[((size_t)((rb1 + tx) * 3 + c)) * NBINS + t];
    }
    #pragma unroll
    for (int tx = 0; tx < 8; ++tx) {
        int txn = (tx < 7) ? tx + 1 : 7;
        Pack[tx][t] = (unsigned)(iL1[tx] | (iL1[txn] << 8) | (iL0[tx] << 16) | (iL0[txn] << 24));
    }
    Pack[8][t] = (unsigned)(iL1[0] | (iL1[0] << 8) | (iL0[0] << 16) | (iL0[0] << 24));
    __syncthreads();

    const int x4f = t & 127;
    const int x   = x4f * 4;
    const int tx_sel = (x < 32) ? 8 : ((x >= 480) ? 7 : ((x - 32) >> 6));
    const unsigned int* __restrict__ Row = &Pack[tx_sel][0];
    float wxv[4];
    #pragma unroll
    for (int i = 0; i < 4; ++i) {
        const int xx = x + i;
        wxv[i] = (xx < 32 || xx >= 480) ? 1.0f
               : (float)(63 - ((xx - 32) & 63)) * (1.0f / 63.0f);
    }

    const size_t pb = (((size_t)plane) << 18) + (size_t)y0 * WW;
    const unsigned int* __restrict__ v8w = reinterpret_cast<const unsigned int*>(v8 + pb);
    const f32x4* __restrict__ imgw = reinterpret_cast<const f32x4*>(img + pb);
    f32x4* __restrict__ outw = reinterpret_cast<f32x4*>(out + pb);

    #pragma unroll 4
    for (int it = 0; it < 16; ++it) {
        const int fi  = it * 256 + t;
        const int row = fi >> 7;
        const int y   = y0 + row;
        const float wy = (float)(63 - ((y - 32) & 63)) * (1.0f / 63.0f);

        unsigned int w;
        float pix[4];
        if constexpr (USE_V8) {
            w = v8w[fi];
        } else {
            f32x4 f = imgw[fi];
            pix[0] = f.x; pix[1] = f.y; pix[2] = f.z; pix[3] = f.w;
        }

        f32x4 res;
        #pragma unroll
        for (int i = 0; i < 4; ++i) {
            int vv;
            if constexpr (USE_V8) vv = (w >> (8 * i)) & 255;
            else                  vv = min(max((int)floorf(pix[i] * 255.0f), 0), 255);
            const unsigned int raw = Row[vv];
            const float l1a = (float)(raw & 255u);
            const float l1b = (float)((raw >> 8) & 255u);
            const float l0a = (float)((raw >> 16) & 255u);
            const float l0b = (float)(raw >> 24);
            const float r0 = fmaf(wy, l0a - l1a, l1a);
            const float r1 = fmaf(wy, l0b - l1b, l1b);
            res[i] = fmaf(wxv[i], r0 - r1, r1) * (1.0f / 255.0f);
        }
        outw[fi] = res;
    }
}

extern "C" void kernel_launch(void* const* d_in, const int* in_sizes, int n_in,
                              void* d_out, int out_size, void* d_ws, size_t ws_size,
                              hipStream_t stream) {
    const float* img  = (const float*)d_in[0];
    float*       out  = (float*)d_out;
    float*       luts = (float*)d_ws;
    unsigned char* v8 = (unsigned char*)d_ws + (size_t)LUTS_FLOATS * 4;

    const bool use_v8 = ws_size >= (size_t)LUTS_FLOATS * 4 + V8_BYTES;

    hipError_t err = hipErrorUnknown;
    if (use_v8) {
        void* args[] = { (void*)&img, (void*)&luts, (void*)&v8, (void*)&out };
        err = hipLaunchCooperativeKernel((const void*)clahe_fused2,
                                         dim3(768), dim3(256), args, 0, stream);
    }
    if (err != hipSuccess) {
        // Fallback: known-good R12 two-kernel path
        clahe_hist_lut_stripe<<<768, 256, 0, stream>>>(img, luts, v8, use_v8 ? 1 : 0);
        if (use_v8)
            clahe_apply_band<true><<<1536, 256, 0, stream>>>(img, v8, luts, out);
        else
            clahe_apply_band<false><<<1536, 256, 0, stream>>>(img, v8, luts, out);
    }
}

// Round 14
// 53.034 us; speedup vs baseline: 3.4747x; 3.4747x over previous
//
#include <hip/hip_runtime.h>

// CLAHE: B=32, C=3, H=W=512, GRID=8x8 -> TILE=64x64 (4096 px), NUM_BINS=256,
// CLIP_LIMIT=40 -> clip value = 640.
// d_ws layout: [0, 6.29MB) f32 LUTs (lut_idx = ((b*8+ty)*8+tx)*3 + c),
//              [6.29MB, +25.2MB) u8 quantized image v = clip(floor(img*255)).
// R14 = R12 with k2 re-gridded: 16-row bands, 3072 blocks (was 32-row/1536).
// k2 was grid-limited to 6 blocks/CU (occupancy 44%, VALUBusy 27% = latency
// bound per R8 counters); 12 blocks/CU of work -> ~8 resident -> 32 waves/CU.
// Cooperative fusion is DEAD on this stack (R5: 217us, R13: 184us, ~4x throttle).

#define NBINS  256
#define TILE   64
#define CH     3
#define HH     512
#define WW     512
#define CLIPV  640
#define PIXELS 4096   // per tile

#define LUTS_FLOATS (32 * 8 * 8 * 3 * NBINS)          // 1,572,864
#define V8_BYTES    ((size_t)32 * 3 * HH * WW)        // 25,165,824

typedef float f32x4 __attribute__((ext_vector_type(4)));

// ---------------- Kernel 1: stripe histogram + clip + cumsum -> LUT ------------
// One block per (plane, tile-row): 96*8 = 768 blocks. At combined-BW floor
// (18.4us vs 18.3 model) — do not touch.
__global__ __launch_bounds__(256) void clahe_hist_lut_stripe(const float* __restrict__ img,
                                                             float* __restrict__ luts,
                                                             unsigned char* __restrict__ v8,
                                                             int write_v8) {
    const int t     = threadIdx.x;
    const int bid   = blockIdx.x;        // = plane*8 + ty
    const int ty    = bid & 7;
    const int plane = bid >> 3;          // b*3 + c
    const int c     = plane % 3;
    const int bb    = plane / 3;

    __shared__ unsigned int hist[8][NBINS];   // 8 KB
    #pragma unroll
    for (int h = 0; h < 8; ++h) hist[h][t] = 0u;
    __syncthreads();

    const size_t base = ((size_t)plane * HH + (size_t)ty * TILE) * WW;  // float offset
    const f32x4* __restrict__ src  = reinterpret_cast<const f32x4*>(img + base);
    uchar4*      __restrict__ dst8 = reinterpret_cast<uchar4*>(v8 + base);

    // stripe = 64 rows * 128 float4 = 8192 float4; 256 threads x 32 iters.
    #pragma unroll 4
    for (int it = 0; it < 32; ++it) {
        const int f = it * 256 + t;          // linear float4 index in stripe
        const f32x4 v = src[f];
        const int tile = (f & 127) >> 4;     // 4 px of a float4 share one tile
        atomicAdd(&hist[tile][min(max((int)floorf(v.x * 256.0f), 0), 255)], 1u);
        atomicAdd(&hist[tile][min(max((int)floorf(v.y * 256.0f), 0), 255)], 1u);
        atomicAdd(&hist[tile][min(max((int)floorf(v.z * 256.0f), 0), 255)], 1u);
        atomicAdd(&hist[tile][min(max((int)floorf(v.w * 256.0f), 0), 255)], 1u);
        if (write_v8) {
            uchar4 q;
            q.x = (unsigned char)min(max((int)floorf(v.x * 255.0f), 0), 255);
            q.y = (unsigned char)min(max((int)floorf(v.y * 255.0f), 0), 255);
            q.z = (unsigned char)min(max((int)floorf(v.z * 255.0f), 0), 255);
            q.w = (unsigned char)min(max((int)floorf(v.w * 255.0f), 0), 255);
            dst8[f] = q;
        }
    }
    __syncthreads();

    // Each of the 4 waves scans 2 histograms (256 bins = 4 chunks of 64).
    const int lane = t & 63;
    const int wid  = t >> 6;

    #pragma unroll
    for (int s = 0; s < 2; ++s) {
        const int h = wid * 2 + s;
        int carry = 0;
        int incl[4];
        #pragma unroll
        for (int ch = 0; ch < 4; ++ch) {
            int v = min((int)hist[h][ch * 64 + lane], CLIPV);
            #pragma unroll
            for (int off = 1; off < 64; off <<= 1) {
                int n = __shfl_up(v, off, 64);
                if (lane >= off) v += n;
            }
            incl[ch] = carry + v;
            carry += __shfl(v, 63, 64);      // chunk total from lane 63
        }
        const int total    = carry;
        const int excess   = PIXELS - total;           // >= 0
        const int residual = excess & 255;
        const int redist   = excess >> 8;
        const int job = ((bb * 8 + ty) * 8 + h) * 3 + c;
        float* __restrict__ dst = luts + (size_t)job * NBINS;
        #pragma unroll
        for (int ch = 0; ch < 4; ++ch) {
            const int bin = ch * 64 + lane;
            // inclusive cumsum of (clipped + redist + (bin<residual ? 1 : 0));
            // (nb-1)/pixels = 255/4096 exact in fp32; product <= 255 exact.
            const int cum = incl[ch] + redist * (bin + 1) + min(bin + 1, residual);
            dst[bin] = floorf(fminf((float)cum * (255.0f / 4096.0f), 255.0f));
        }
    }
}

// ---------------- Kernel 2: bilinear LUT application (16-row bands) ------------
// One block = 16-row group of one (b,c) plane. All 16-aligned groups lie
// within one ty-band (breakpoints 32+64k and 480 are multiples of 32, and no
// multiple of 32 falls strictly inside a 16-aligned 16-row window).
// Pack[tx][v] = L1[tx] | L1[tx+1]<<8 | L0[tx]<<16 | L0[tx+1]<<24 (exact ints).
// Entry 7 dups (L7,L7); entry 8 dups col0 for the left edge (wx-invariant).
// Thread t: float4 fi = it*256+t -> 1KB fully-coalesced wave stores; v8 read
// one u32/thread; x-geometry thread-constant. 3072 blocks -> 12 blocks/CU of
// work (~8 resident, 32 waves/CU) to hide the load->gather->store chain.
template<bool USE_V8>
__global__ __launch_bounds__(256) void clahe_apply_band(const float* __restrict__ img,
                                                        const unsigned char* __restrict__ v8,
                                                        const float* __restrict__ luts,
                                                        float* __restrict__ out) {
    __shared__ unsigned int Pack[9][NBINS];   // 9 KB

    const int t     = threadIdx.x;
    const int bid   = blockIdx.x;
    const int g     = bid & 31;           // 16-row group 0..31
    const int plane = bid >> 5;           // b*3 + c, 0..95
    const int c     = plane % 3;
    const int bb    = plane / 3;
    const int y0    = g * 16;

    int ty0, ty1;
    if (y0 < 32)        { ty0 = 0; ty1 = 0; }
    else if (y0 >= 480) { ty0 = 7; ty1 = 7; }
    else                { ty0 = (y0 - 32) >> 6; ty1 = ty0 + 1; }

    const int rb0 = (bb * 8 + ty0) * 8;
    const int rb1 = (bb * 8 + ty1) * 8;

    // 16 coalesced 1KB loads (v = t); LUT values are integral 0..255.
    int iL0[8], iL1[8];
    #pragma unroll
    for (int tx = 0; tx < 8; ++tx) {
        iL0[tx] = (int)luts[((size_t)((rb0 + tx) * 3 + c)) * NBINS + t];
        iL1[tx] = (int)luts[((size_t)((rb1 + tx) * 3 + c)) * NBINS + t];
    }
    #pragma unroll
    for (int tx = 0; tx < 8; ++tx) {
        int txn = (tx < 7) ? tx + 1 : 7;
        Pack[tx][t] = (unsigned)(iL1[tx] | (iL1[txn] << 8) | (iL0[tx] << 16) | (iL0[txn] << 24));
    }
    Pack[8][t] = (unsigned)(iL1[0] | (iL1[0] << 8) | (iL0[0] << 16) | (iL0[0] << 24));
    __syncthreads();

    // Thread-constant x geometry: this thread always covers pixels x..x+3.
    const int x4f = t & 127;              // float4 column 0..127
    const int x   = x4f * 4;
    const int tx_sel = (x < 32) ? 8 : ((x >= 480) ? 7 : ((x - 32) >> 6));
    const unsigned int* __restrict__ Row = &Pack[tx_sel][0];
    float wxv[4];
    #pragma unroll
    for (int i = 0; i < 4; ++i) {
        const int xx = x + i;
        wxv[i] = (xx < 32 || xx >= 480) ? 1.0f
               : (float)(63 - ((xx - 32) & 63)) * (1.0f / 63.0f);
    }

    const size_t pb = (((size_t)plane) << 18) + (size_t)y0 * WW;   // float offset
    const unsigned int* __restrict__ v8w = reinterpret_cast<const unsigned int*>(v8 + pb);
    const f32x4* __restrict__ imgw = reinterpret_cast<const f32x4*>(img + pb);
    f32x4* __restrict__ outw = reinterpret_cast<f32x4*>(out + pb);

    // band = 16 rows * 128 float4 = 2048 float4; 8 iters x 256 threads.
    #pragma unroll 4
    for (int it = 0; it < 8; ++it) {
        const int fi  = it * 256 + t;     // lane-consecutive float4 index
        const int row = fi >> 7;
        const int y   = y0 + row;
        // On edge bands L0==L1 -> slope 0 -> wy's value irrelevant; safe.
        const float wy = (float)(63 - ((y - 32) & 63)) * (1.0f / 63.0f);

        unsigned int w;
        float pix[4];
        if constexpr (USE_V8) {
            w = v8w[fi];
        } else {
            f32x4 f = imgw[fi];
            pix[0] = f.x; pix[1] = f.y; pix[2] = f.z; pix[3] = f.w;
        }

        f32x4 res;
        #pragma unroll
        for (int i = 0; i < 4; ++i) {
            int vv;
            if constexpr (USE_V8) vv = (w >> (8 * i)) & 255;
            else                  vv = min(max((int)floorf(pix[i] * 255.0f), 0), 255);
            const unsigned int raw = Row[vv];
            const float l1a = (float)(raw & 255u);           // v_cvt_f32_ubyte0
            const float l1b = (float)((raw >> 8) & 255u);    // v_cvt_f32_ubyte1
            const float l0a = (float)((raw >> 16) & 255u);   // v_cvt_f32_ubyte2
            const float l0b = (float)(raw >> 24);            // v_cvt_f32_ubyte3
            const float r0 = fmaf(wy, l0a - l1a, l1a);       // col tx0 value
            const float r1 = fmaf(wy, l0b - l1b, l1b);       // col tx1 value
            res[i] = fmaf(wxv[i], r0 - r1, r1) * (1.0f / 255.0f);
        }
        outw[fi] = res;
    }
}

extern "C" void kernel_launch(void* const* d_in, const int* in_sizes, int n_in,
                              void* d_out, int out_size, void* d_ws, size_t ws_size,
                              hipStream_t stream) {
    const float* img  = (const float*)d_in[0];
    float*       out  = (float*)d_out;
    float*       luts = (float*)d_ws;
    unsigned char* v8 = (unsigned char*)d_ws + (size_t)LUTS_FLOATS * 4;

    const bool use_v8 = ws_size >= (size_t)LUTS_FLOATS * 4 + V8_BYTES;

    // Kernel 1: one block per (plane, tile-row) stripe: 96*8 = 768 blocks
    clahe_hist_lut_stripe<<<768, 256, 0, stream>>>(img, luts, v8, use_v8 ? 1 : 0);
    // Kernel 2: one block per (plane, 16-row group): 96 * 32 = 3072 blocks
    if (use_v8)
        clahe_apply_band<true><<<3072, 256, 0, stream>>>(img, v8, luts, out);
    else
        clahe_apply_band<false><<<3072, 256, 0, stream>>>(img, v8, luts, out);
}

// Round 17
// 50.223 us; speedup vs baseline: 3.6692x; 1.0560x over previous
//
#include <hip/hip_runtime.h>

// CLAHE: B=32, C=3, H=W=512, GRID=8x8 -> TILE=64x64 (4096 px), NUM_BINS=256,
// CLIP_LIMIT=40 -> clip value = 640.
// d_ws layout: [0, 6.29MB) f32 LUTs (lut_idx = ((b*8+ty)*8+tx)*3 + c),
//              [6.29MB, +25.2MB) u8 quantized image v = clip(floor(img*255)).
// R17 = R15/R16 resubmitted (2x infra failure): k2 widened to 512-thread
// blocks (same 1536 blocks/32-row bands): 8 waves x 4 resident blocks/CU =
// 32 waves/CU (was ~14, occ 44%). Staging events unchanged, split across halves.
// R14 falsified "more blocks" (dup staging cost > occupancy gain).
// Cooperative fusion DEAD on this stack (R5: 217us, R13: 184us).

#define NBINS  256
#define TILE   64
#define CH     3
#define HH     512
#define WW     512
#define CLIPV  640
#define PIXELS 4096   // per tile

#define LUTS_FLOATS (32 * 8 * 8 * 3 * NBINS)          // 1,572,864
#define V8_BYTES    ((size_t)32 * 3 * HH * WW)        // 25,165,824

typedef float f32x4 __attribute__((ext_vector_type(4)));

// ---------------- Kernel 1: stripe histogram + clip + cumsum -> LUT ------------
// One block per (plane, tile-row): 96*8 = 768 blocks. At combined-BW floor
// (18.4us vs 18.3 model) — unchanged from R12.
__global__ __launch_bounds__(256) void clahe_hist_lut_stripe(const float* __restrict__ img,
                                                             float* __restrict__ luts,
                                                             unsigned char* __restrict__ v8,
                                                             int write_v8) {
    const int t     = threadIdx.x;
    const int bid   = blockIdx.x;        // = plane*8 + ty
    const int ty    = bid & 7;
    const int plane = bid >> 3;          // b*3 + c
    const int c     = plane % 3;
    const int bb    = plane / 3;

    __shared__ unsigned int hist[8][NBINS];   // 8 KB
    #pragma unroll
    for (int h = 0; h < 8; ++h) hist[h][t] = 0u;
    __syncthreads();

    const size_t base = ((size_t)plane * HH + (size_t)ty * TILE) * WW;  // float offset
    const f32x4* __restrict__ src  = reinterpret_cast<const f32x4*>(img + base);
    uchar4*      __restrict__ dst8 = reinterpret_cast<uchar4*>(v8 + base);

    // stripe = 64 rows * 128 float4 = 8192 float4; 256 threads x 32 iters.
    #pragma unroll 4
    for (int it = 0; it < 32; ++it) {
        const int f = it * 256 + t;          // linear float4 index in stripe
        const f32x4 v = src[f];
        const int tile = (f & 127) >> 4;     // 4 px of a float4 share one tile
        atomicAdd(&hist[tile][min(max((int)floorf(v.x * 256.0f), 0), 255)], 1u);
        atomicAdd(&hist[tile][min(max((int)floorf(v.y * 256.0f), 0), 255)], 1u);
        atomicAdd(&hist[tile][min(max((int)floorf(v.z * 256.0f), 0), 255)], 1u);
        atomicAdd(&hist[tile][min(max((int)floorf(v.w * 256.0f), 0), 255)], 1u);
        if (write_v8) {
            uchar4 q;
            q.x = (unsigned char)min(max((int)floorf(v.x * 255.0f), 0), 255);
            q.y = (unsigned char)min(max((int)floorf(v.y * 255.0f), 0), 255);
            q.z = (unsigned char)min(max((int)floorf(v.z * 255.0f), 0), 255);
            q.w = (unsigned char)min(max((int)floorf(v.w * 255.0f), 0), 255);
            dst8[f] = q;
        }
    }
    __syncthreads();

    // Each of the 4 waves scans 2 histograms (256 bins = 4 chunks of 64).
    const int lane = t & 63;
    const int wid  = t >> 6;

    #pragma unroll
    for (int s = 0; s < 2; ++s) {
        const int h = wid * 2 + s;
        int carry = 0;
        int incl[4];
        #pragma unroll
        for (int ch = 0; ch < 4; ++ch) {
            int v = min((int)hist[h][ch * 64 + lane], CLIPV);
            #pragma unroll
            for (int off = 1; off < 64; off <<= 1) {
                int n = __shfl_up(v, off, 64);
                if (lane >= off) v += n;
            }
            incl[ch] = carry + v;
            carry += __shfl(v, 63, 64);      // chunk total from lane 63
        }
        const int total    = carry;
        const int excess   = PIXELS - total;           // >= 0
        const int residual = excess & 255;
        const int redist   = excess >> 8;
        const int job = ((bb * 8 + ty) * 8 + h) * 3 + c;
        float* __restrict__ dst = luts + (size_t)job * NBINS;
        #pragma unroll
        for (int ch = 0; ch < 4; ++ch) {
            const int bin = ch * 64 + lane;
            // inclusive cumsum of (clipped + redist + (bin<residual ? 1 : 0));
            // (nb-1)/pixels = 255/4096 exact in fp32; product <= 255 exact.
            const int cum = incl[ch] + redist * (bin + 1) + min(bin + 1, residual);
            dst[bin] = floorf(fminf((float)cum * (255.0f / 4096.0f), 255.0f));
        }
    }
}

// ---------------- Kernel 2: bilinear LUT application (512-thread blocks) -------
// One block = 32-row band of one (b,c) plane (all rows share ty0/ty1; band
// breakpoints 32+64k, 480 are multiples of 32).
// Pack[tx][v] = L1[tx] | L1[tx+1]<<8 | L0[tx]<<16 | L0[tx+1]<<24 (exact ints).
// Entry 7 dups (L7,L7); entry 8 dups col0 for the left edge (wx-invariant).
// 512 threads: staging split across halves (half h stages tx 4h..4h+3, loading
// tx 4h..4h+4 clamped); apply fi = it*512 + t keeps wave stores 1KB contiguous
// and x-geometry thread-constant (fi&127 == t&127). 8 float4/thread.
template<bool USE_V8>
__global__ __launch_bounds__(512) void clahe_apply_band(const float* __restrict__ img,
                                                        const unsigned char* __restrict__ v8,
                                                        const float* __restrict__ luts,
                                                        float* __restrict__ out) {
    __shared__ unsigned int Pack[9][NBINS];   // 9 KB

    const int t     = threadIdx.x;            // 0..511
    const int bid   = blockIdx.x;
    const int g     = bid & 15;               // 32-row band 0..15
    const int plane = bid >> 4;               // b*3 + c, 0..95
    const int c     = plane % 3;
    const int bb    = plane / 3;
    const int y0    = g * 32;

    int ty0, ty1;
    if (y0 < 32)        { ty0 = 0; ty1 = 0; }
    else if (y0 >= 480) { ty0 = 7; ty1 = 7; }
    else                { ty0 = (y0 - 32) >> 6; ty1 = ty0 + 1; }

    const int rb0 = (bb * 8 + ty0) * 8;
    const int rb1 = (bb * 8 + ty1) * 8;

    // Staging: half h (= t>>8) covers tx 4h..4h+3; loads tx 4h..4h+4 (clamp 7).
    const int tt   = t & 255;                 // v index
    const int half = t >> 8;                  // 0 or 1
    int iL0[5], iL1[5];
    #pragma unroll
    for (int j = 0; j < 5; ++j) {
        const int txc = min(half * 4 + j, 7);
        iL0[j] = (int)luts[((size_t)((rb0 + txc) * 3 + c)) * NBINS + tt];
        iL1[j] = (int)luts[((size_t)((rb1 + txc) * 3 + c)) * NBINS + tt];
    }
    #pragma unroll
    for (int j = 0; j < 4; ++j) {
        const int tx = half * 4 + j;
        Pack[tx][tt] = (unsigned)(iL1[j] | (iL1[j + 1] << 8) |
                                  (iL0[j] << 16) | (iL0[j + 1] << 24));
    }
    if (half == 0)
        Pack[8][tt] = (unsigned)(iL1[0] | (iL1[0] << 8) | (iL0[0] << 16) | (iL0[0] << 24));
    __syncthreads();

    // Thread-constant x geometry: this thread always covers pixels x..x+3.
    const int x4f = t & 127;              // float4 column 0..127 (512 ≡ 0 mod 128)
    const int x   = x4f * 4;
    const int tx_sel = (x < 32) ? 8 : ((x >= 480) ? 7 : ((x - 32) >> 6));
    const unsigned int* __restrict__ Row = &Pack[tx_sel][0];
    float wxv[4];
    #pragma unroll
    for (int i = 0; i < 4; ++i) {
        const int xx = x + i;
        wxv[i] = (xx < 32 || xx >= 480) ? 1.0f
               : (float)(63 - ((xx - 32) & 63)) * (1.0f / 63.0f);
    }

    const size_t pb = (((size_t)plane) << 18) + (size_t)y0 * WW;   // float offset
    const unsigned int* __restrict__ v8w = reinterpret_cast<const unsigned int*>(v8 + pb);
    const f32x4* __restrict__ imgw = reinterpret_cast<const f32x4*>(img + pb);
    f32x4* __restrict__ outw = reinterpret_cast<f32x4*>(out + pb);

    // band = 32 rows * 128 float4 = 4096 float4; 8 iters x 512 threads.
    #pragma unroll 4
    for (int it = 0; it < 8; ++it) {
        const int fi  = it * 512 + t;     // lane-consecutive float4 index
        const int row = fi >> 7;          // = it*4 + (t>>7)
        const int y   = y0 + row;
        // On edge bands L0==L1 -> slope 0 -> wy's value irrelevant; safe.
        const float wy = (float)(63 - ((y - 32) & 63)) * (1.0f / 63.0f);

        unsigned int w;
        float pix[4];
        if constexpr (USE_V8) {
            w = v8w[fi];
        } else {
            f32x4 f = imgw[fi];
            pix[0] = f.x; pix[1] = f.y; pix[2] = f.z; pix[3] = f.w;
        }

        f32x4 res;
        #pragma unroll
        for (int i = 0; i < 4; ++i) {
            int vv;
            if constexpr (USE_V8) vv = (w >> (8 * i)) & 255;
            else                  vv = min(max((int)floorf(pix[i] * 255.0f), 0), 255);
            const unsigned int raw = Row[vv];
            const float l1a = (float)(raw & 255u);           // v_cvt_f32_ubyte0
            const float l1b = (float)((raw >> 8) & 255u);    // v_cvt_f32_ubyte1
            const float l0a = (float)((raw >> 16) & 255u);   // v_cvt_f32_ubyte2
            const float l0b = (float)(raw >> 24);            // v_cvt_f32_ubyte3
            const float r0 = fmaf(wy, l0a - l1a, l1a);       // col tx0 value
            const float r1 = fmaf(wy, l0b - l1b, l1b);       // col tx1 value
            res[i] = fmaf(wxv[i], r0 - r1, r1) * (1.0f / 255.0f);
        }
        outw[fi] = res;
    }
}

extern "C" void kernel_launch(void* const* d_in, const int* in_sizes, int n_in,
                              void* d_out, int out_size, void* d_ws, size_t ws_size,
                              hipStream_t stream) {
    const float* img  = (const float*)d_in[0];
    float*       out  = (float*)d_out;
    float*       luts = (float*)d_ws;
    unsigned char* v8 = (unsigned char*)d_ws + (size_t)LUTS_FLOATS * 4;

    const bool use_v8 = ws_size >= (size_t)LUTS_FLOATS * 4 + V8_BYTES;

    // Kernel 1: one block per (plane, tile-row) stripe: 96*8 = 768 blocks
    clahe_hist_lut_stripe<<<768, 256, 0, stream>>>(img, luts, v8, use_v8 ? 1 : 0);
    // Kernel 2: one block per (plane, 32-row band): 96*16 = 1536 blocks x 512
    if (use_v8)
        clahe_apply_band<true><<<1536, 512, 0, stream>>>(img, v8, luts, out);
    else
        clahe_apply_band<false><<<1536, 512, 0, stream>>>(img, v8, luts, out);
}